// Round 13
// baseline (456.189 us; speedup 1.0000x reference)
//
#include <hip/hip_runtime.h>
#include <hip/hip_bf16.h>
#include <stdint.h>

#define M_TOTAL 16384   // BATCH * SEQ
#define N_TOTAL 4096    // OUT_FEATURES
#define K_TOTAL 4096    // IN_FEATURES

#define BM 256
#define BN 256
#define BKI 64                   // int8 K per ring slot
#define NTI (K_TOTAL / BKI)      // 64 K-steps

typedef __attribute__((ext_vector_type(4))) float f32x4;
typedef __attribute__((ext_vector_type(4))) int   i32x4;

// ---------- x fp32 (M,K) -> int8 per-row symmetric quant + qrow ----------
__global__ __launch_bounds__(256) void quant_x_kernel(
    const float* __restrict__ x, signed char* __restrict__ xq,
    float* __restrict__ qrow) {
  __shared__ float red[8];
  const int row = blockIdx.x;                      // 16384 rows
  const int tid = threadIdx.x;
  const float* xr = x + (size_t)row * K_TOTAL;
  const f32x4* xv = (const f32x4*)xr;

  f32x4 v[4];
  float mx = 0.f;
#pragma unroll
  for (int j = 0; j < 4; ++j) {
    v[j] = xv[j * 256 + tid];                      // coalesced float4
#pragma unroll
    for (int e = 0; e < 4; ++e) mx = fmaxf(mx, fabsf(v[j][e]));
  }
#pragma unroll
  for (int off = 32; off > 0; off >>= 1) mx = fmaxf(mx, __shfl_xor(mx, off));
  if ((tid & 63) == 0) red[tid >> 6] = mx;
  __syncthreads();
  if (tid == 0) {
    float m2 = fmaxf(fmaxf(red[0], red[1]), fmaxf(red[2], red[3]));
    red[4] = m2;
    qrow[row] = m2 * (1.f / 127.f);
  }
  __syncthreads();
  const float rmax = red[4];
  const float rq = rmax > 0.f ? 127.f / rmax : 0.f;

  int* oq = (int*)(xq + (size_t)row * K_TOTAL);
#pragma unroll
  for (int j = 0; j < 4; ++j) {
    int b0 = (int)rintf(v[j][0] * rq) & 0xff;
    int b1 = (int)rintf(v[j][1] * rq) & 0xff;
    int b2 = (int)rintf(v[j][2] * rq) & 0xff;
    int b3 = (int)rintf(v[j][3] * rq) & 0xff;
    oq[j * 256 + tid] = b0 | (b1 << 8) | (b2 << 16) | (b3 << 24);
  }
}

// ---------- packed int4 -> int8 in MFMA-frag-packed order ----------
// Bp unit u (16 B): lane = u&63, nf = (u>>6)&7, tt = (u>>9)&63, wnb = u>>15
// (wnb = bn*2+wn, 0..31). Unit holds W rows o = (wnb>>1)*256+(wnb&1)*128+
// nf*16+(lane&15), k-bytes tt*64+(lane>>4)*16 .. +15.
__global__ __launch_bounds__(256) void dequant_pack_kernel(
    const int* __restrict__ wq, signed char* __restrict__ Bp) {
  const int u0 = (blockIdx.x * 256 + threadIdx.x) * 4;
#pragma unroll
  for (int i = 0; i < 4; ++i) {
    const int u = u0 + i;                 // < 1048576
    const int lane = u & 63;
    const int nf = (u >> 6) & 7;
    const int tt = (u >> 9) & 63;
    const int wnb = u >> 15;              // 0..31
    const int o = (wnb >> 1) * 256 + (wnb & 1) * 128 + nf * 16 + (lane & 15);
    const int k = tt * 64 + (lane >> 4) * 16;
    const int* src = wq + (size_t)o * (K_TOTAL / 2) + (k >> 1);   // 8 ints
    i32x4 s0 = *(const i32x4*)src;
    i32x4 s1 = *(const i32x4*)(src + 4);
    int wds[4];
#pragma unroll
    for (int h = 0; h < 2; ++h) {
      i32x4 s = h ? s1 : s0;
#pragma unroll
      for (int p = 0; p < 2; ++p) {
        int ba = s[2 * p], bb = s[2 * p + 1];
        int lo0 = (((ba & 0xF) ^ 8) - 8) & 0xff;
        int hi0 = ((((ba >> 4) & 0xF) ^ 8) - 8) & 0xff;
        int lo1 = (((bb & 0xF) ^ 8) - 8) & 0xff;
        int hi1 = ((((bb >> 4) & 0xF) ^ 8) - 8) & 0xff;
        wds[h * 2 + p] = lo0 | (hi0 << 8) | (lo1 << 16) | (hi1 << 24);
      }
    }
    i32x4 o4; o4[0] = wds[0]; o4[1] = wds[1]; o4[2] = wds[2]; o4[3] = wds[3];
    *(i32x4*)(Bp + (size_t)u * 16) = o4;
  }
}

#define MFMAI(a, b, c) __builtin_amdgcn_mfma_i32_16x16x64_i8((a), (b), (c), 0, 0, 0)
#define SCHED0() __builtin_amdgcn_sched_barrier(0)

// int8 GEMM: 256x256, 8 waves as 4x2 (per-wave 64x128). A via 4-slot LDS ring
// (4 ds_read/wave/tile, r11 swizzle); B streamed global->reg from frag-packed
// layout (8 x 1KB coalesced loads, L2-resident per XCD). One barrier/tile.
// vmem FIFO per tile: [B(t):8][AstageGLL(t+2):2] => steady gate vmcnt(2)
// before MFMA drains B(t)+Astage(t+1), leaves Astage(t+2) in flight.
__global__ __launch_bounds__(512, 2) void gemm256_i8_kernel(
    const signed char* __restrict__ A8,   // M x K int8
    const signed char* __restrict__ Bp,   // frag-packed B
    const float* __restrict__ qrow,
    const float* __restrict__ scales,
    const float* __restrict__ bias,
    float* __restrict__ C) {
  __shared__ signed char ldsA[4][BM * BKI];   // 4 x 16 KB = 64 KB

  const int t  = threadIdx.x;
  const int l  = t & 63;
  const int w  = t >> 6;
  const int wm = w >> 1;        // 0..3 (64-row band)
  const int wn = w & 1;         // 0..1 (128-col band)
  const int fr = l & 15;
  const int kg = l >> 4;        // 0..3
  const int sxs = (kg ^ ((fr >> 1) & 3)) << 4;   // swizzled byte slot (64B row)

  const int wg = blockIdx.x;                        // nwg = 1024
  const int bm = (wg & 7) * 8 + ((wg >> 3) & 7);    // 0..63
  const int bn = wg >> 6;                           // 0..15

  // A staging: thread t -> stored (row g*128 + (t>>2), slot t&3); source
  // pre-swizzled: logical slot (t&3) ^ ((t>>3)&3).
  const int rr   = t >> 2;                 // 0..127
  const int ssrc = ((t & 3) ^ ((t >> 3) & 3)) << 4;
  const signed char* pa = A8 + (size_t)(bm * BM + rr) * K_TOTAL + ssrc;

#define GLL(gp, lp) __builtin_amdgcn_global_load_lds( \
      (const __attribute__((address_space(1))) unsigned int*)(gp), \
      (__attribute__((address_space(3))) unsigned int*)(lp), 16, 0, 0)

  auto stageA = [&](int slot, size_t kt) {
    GLL(pa + kt,                         &ldsA[slot][t * 16]);
    GLL(pa + (size_t)128 * K_TOTAL + kt, &ldsA[slot][8192 + t * 16]);
  };

  // Packed-B wave base: frag (t0, nf) at pB + (t0*8 + nf)*1024.
  const signed char* pB = Bp + (size_t)(bn * 2 + wn) * 524288 + l * 16;

  i32x4 acc[4][8] = {};
  i32x4 a_[4], b_[8];

  // Prologue: stage slots 0,1; drain slot 0 (leave slot 1 in flight).
  stageA(0, 0); stageA(1, BKI);
  asm volatile("s_waitcnt vmcnt(2)" ::: "memory");
  SCHED0();

  const int abase = (wm * 64 + fr) * BKI + sxs;

  for (int t0 = 0; t0 < NTI; ++t0) {
    SCHED0();
    __builtin_amdgcn_s_barrier();             // slot t0&3 published (all waves)
    SCHED0();
    // B(t0): 8 coalesced 1KB reg-loads (vmem, L2-resident)
    const signed char* pBt = pB + (size_t)t0 * 8192;
#pragma unroll
    for (int nf = 0; nf < 8; ++nf)
      b_[nf] = *(const i32x4*)(pBt + nf * 1024);
    SCHED0();
    // A: 4 ds_read_b128 from ring slot
    const signed char* Ab = &ldsA[t0 & 3][abase];
#pragma unroll
    for (int mf = 0; mf < 4; ++mf)
      a_[mf] = *(const i32x4*)&Ab[mf * 16 * BKI];
    SCHED0();
    if (t0 + 2 < NTI) stageA((t0 + 2) & 3, (size_t)(t0 + 2) * BKI);
    SCHED0();
    asm volatile("s_waitcnt lgkmcnt(0)" ::: "memory");   // a_ ready
    if (t0 < NTI - 2) { asm volatile("s_waitcnt vmcnt(2)" ::: "memory"); }
    else              { asm volatile("s_waitcnt vmcnt(0)" ::: "memory"); }
    SCHED0();
    __builtin_amdgcn_s_setprio(1);
#pragma unroll
    for (int mf = 0; mf < 4; ++mf)
#pragma unroll
      for (int nf = 0; nf < 8; ++nf)
        acc[mf][nf] = MFMAI(a_[mf], b_[nf], acc[mf][nf]);
    __builtin_amdgcn_s_setprio(0);
    SCHED0();
  }

  // Epilogue: C/D layout col = lane&15, row = (lane>>4)*4 + reg (dtype-indep).
  const int row0 = bm * BM + wm * 64 + kg * 4;
  const int col0 = bn * BN + wn * 128 + fr;
  float qv[4][4];
#pragma unroll
  for (int m = 0; m < 4; ++m)
#pragma unroll
    for (int r = 0; r < 4; ++r) qv[m][r] = qrow[row0 + m * 16 + r];
#pragma unroll
  for (int nf = 0; nf < 8; ++nf) {
    const int gc = col0 + nf * 16;
    const float s  = scales[gc];
    const float bv = bias[gc];
#pragma unroll
    for (int m = 0; m < 4; ++m) {
      const int gr = row0 + m * 16;
#pragma unroll
      for (int r = 0; r < 4; ++r)
        C[(size_t)(gr + r) * N_TOTAL + gc] = (float)acc[m][nf][r] * (qv[m][r] * s) + bv;
    }
  }
#undef GLL
}

// Fallback if workspace is too small: correct but slow.
__global__ void naive_int4_kernel(const float* __restrict__ x,
                                  const int* __restrict__ wq,
                                  const float* __restrict__ scales,
                                  const float* __restrict__ bias,
                                  float* __restrict__ out) {
  size_t idx = (size_t)blockIdx.x * blockDim.x + threadIdx.x;
  int o = (int)(idx & (N_TOTAL - 1));
  int m = (int)(idx >> 12);
  const float* xr = x + (size_t)m * K_TOTAL;
  const int* wrow = wq + (size_t)o * (K_TOTAL / 2);
  float acc = 0.f;
  for (int j = 0; j < K_TOTAL / 2; ++j) {
    int b = wrow[j];
    int lo = ((b & 0xF) ^ 8) - 8;
    int hi = (((b >> 4) & 0xF) ^ 8) - 8;
    acc += xr[2 * j] * (float)lo + xr[2 * j + 1] * (float)hi;
  }
  out[idx] = acc * scales[o] + bias[o];
}

extern "C" void kernel_launch(void* const* d_in, const int* in_sizes, int n_in,
                              void* d_out, int out_size, void* d_ws, size_t ws_size,
                              hipStream_t stream) {
  const float* x      = (const float*)d_in[0];
  const int*   wq     = (const int*)d_in[1];
  const float* scales = (const float*)d_in[2];
  const float* bias   = (const float*)d_in[3];
  float* out = (float*)d_out;

  const size_t needXQ = (size_t)M_TOTAL * K_TOTAL;                 // 67.1 MB
  const size_t needW8 = (size_t)N_TOTAL * K_TOTAL;                 // 16.8 MB
  const size_t needQ  = (size_t)M_TOTAL * sizeof(float);           // 64 KB

  if (d_ws != nullptr && ws_size >= needXQ + needW8 + needQ) {
    signed char* xq = (signed char*)d_ws;
    signed char* bp = (signed char*)d_ws + needXQ;
    float* qrow = (float*)((char*)d_ws + needXQ + needW8);
    quant_x_kernel<<<M_TOTAL, 256, 0, stream>>>(x, xq, qrow);
    dequant_pack_kernel<<<1024, 256, 0, stream>>>(wq, bp);
    gemm256_i8_kernel<<<(M_TOTAL / BM) * (N_TOTAL / BN), 512, 0, stream>>>(
        xq, bp, qrow, scales, bias, out);
  } else {
    const size_t total = (size_t)M_TOTAL * N_TOTAL;
    naive_int4_kernel<<<(unsigned)(total / 256), 256, 0, stream>>>(x, wq, scales, bias, out);
  }
}

// Round 15
// 377.161 us; speedup vs baseline: 1.2095x; 1.2095x over previous
//
#include <hip/hip_runtime.h>
#include <hip/hip_bf16.h>
#include <stdint.h>

#define M_TOTAL 16384   // BATCH * SEQ
#define N_TOTAL 4096    // OUT_FEATURES
#define K_TOTAL 4096    // IN_FEATURES

#define BM 256
#define BN 128
#define BKI 64                   // int8 K per ring slot
#define NTI (K_TOTAL / BKI)      // 64 K-steps

typedef __attribute__((ext_vector_type(4))) float f32x4;
typedef __attribute__((ext_vector_type(4))) int   i32x4;
typedef __attribute__((ext_vector_type(2))) int   i32x2;

// ---------- x fp32 (M,K) -> int8 per-row symmetric quant + qrow ----------
__global__ __launch_bounds__(256) void quant_x_kernel(
    const float* __restrict__ x, signed char* __restrict__ xq,
    float* __restrict__ qrow) {
  __shared__ float red[8];
  const int row = blockIdx.x;                      // 16384 rows
  const int tid = threadIdx.x;
  const float* xr = x + (size_t)row * K_TOTAL;
  const f32x4* xv = (const f32x4*)xr;

  f32x4 v[4];
  float mx = 0.f;
#pragma unroll
  for (int j = 0; j < 4; ++j) {
    v[j] = xv[j * 256 + tid];                      // coalesced float4
#pragma unroll
    for (int e = 0; e < 4; ++e) mx = fmaxf(mx, fabsf(v[j][e]));
  }
#pragma unroll
  for (int off = 32; off > 0; off >>= 1) mx = fmaxf(mx, __shfl_xor(mx, off));
  if ((tid & 63) == 0) red[tid >> 6] = mx;
  __syncthreads();
  if (tid == 0) {
    float m2 = fmaxf(fmaxf(red[0], red[1]), fmaxf(red[2], red[3]));
    red[4] = m2;
    qrow[row] = m2 * (1.f / 127.f);
  }
  __syncthreads();
  const float rmax = red[4];
  const float rq = rmax > 0.f ? 127.f / rmax : 0.f;

  int* oq = (int*)(xq + (size_t)row * K_TOTAL);
#pragma unroll
  for (int j = 0; j < 4; ++j) {
    int b0 = (int)rintf(v[j][0] * rq) & 0xff;
    int b1 = (int)rintf(v[j][1] * rq) & 0xff;
    int b2 = (int)rintf(v[j][2] * rq) & 0xff;
    int b3 = (int)rintf(v[j][3] * rq) & 0xff;
    oq[j * 256 + tid] = b0 | (b1 << 8) | (b2 << 16) | (b3 << 24);
  }
}

// ---------- packed int4 (one byte per int32 elem) -> int8 (N,K) ----------
__global__ void dequant_w8_kernel(const int* __restrict__ wq,
                                  signed char* __restrict__ w8) {
  const int n = (N_TOTAL * (K_TOTAL / 2)) / 4;     // i32x4 groups
  int idx = blockIdx.x * blockDim.x + threadIdx.x;
  int stride = gridDim.x * blockDim.x;
  const i32x4* wv = (const i32x4*)wq;
  i32x2* ov = (i32x2*)w8;
  for (int i = idx; i < n; i += stride) {
    i32x4 w = wv[i];
    int words[2];
#pragma unroll
    for (int h = 0; h < 2; ++h) {
      int b0 = w[2 * h], b1 = w[2 * h + 1];
      int lo0 = (((b0 & 0xF) ^ 8) - 8) & 0xff;
      int hi0 = ((((b0 >> 4) & 0xF) ^ 8) - 8) & 0xff;
      int lo1 = (((b1 & 0xF) ^ 8) - 8) & 0xff;
      int hi1 = ((((b1 >> 4) & 0xF) ^ 8) - 8) & 0xff;
      words[h] = lo0 | (hi0 << 8) | (lo1 << 16) | (hi1 << 24);
    }
    i32x2 o; o[0] = words[0]; o[1] = words[1];
    ov[i] = o;
  }
}

#define MFMAI(a, b, c) __builtin_amdgcn_mfma_i32_16x16x64_i8((a), (b), (c), 0, 0, 0)
#define SCHED0() __builtin_amdgcn_sched_barrier(0)

// int8 GEMM: 256x128 tile, 4 waves (2x2, per-wave 128x64), 3-slot LDS ring
// (72 KB) -> 2 INDEPENDENT blocks per CU; no cross-block barriers, so one
// block's MFMA phase can run under the other block's DS-read phase (m114).
// Ring invariants (6 GLL/tile): at tile T, stage(T+2) issued -> vmcnt(6)
// drains stage(T+1) -> barrier publishes slot T+1; reads of tile T happened
// after iteration T-1's barrier; lgkm(0) before barrier protects slot reuse.
// FIX vs r14: prologue vmcnt(6)+barrier so tile 0's reads see staged data.
__global__ __launch_bounds__(256, 2) void gemm256_i8_kernel(
    const signed char* __restrict__ A8,   // M x K int8
    const signed char* __restrict__ B8,   // N x K int8
    const float* __restrict__ qrow,
    const float* __restrict__ scales,
    const float* __restrict__ bias,
    float* __restrict__ C) {
  __shared__ signed char ldsA[3][BM * BKI];   // 3 x 16 KB
  __shared__ signed char ldsB[3][BN * BKI];   // 3 x  8 KB   (total 72 KB)

  const int t  = threadIdx.x;
  const int l  = t & 63;
  const int w  = t >> 6;        // wave 0..3
  const int wm = w >> 1;        // 0..1 (128-row band)
  const int wn = w & 1;         // 0..1 (64-col band)
  const int fr = l & 15;
  const int kg = l >> 4;        // 0..3
  const int sxs = (kg ^ ((fr >> 1) & 3)) << 4;   // swizzled byte slot (64B row)

  // XCD map: nwg = 2048 (%8==0). Each XCD owns 8 bm-panels, sweeps bn.
  const int wg = blockIdx.x;
  const int bm = (wg & 7) * 8 + ((wg >> 3) & 7);    // 0..63
  const int bn = wg >> 6;                           // 0..31

  // Staging: thread t -> stored (row g*64 + (t>>2), slot t&3); source
  // pre-swizzled: logical slot (t&3) ^ ((t>>3)&3)  [row bits 1-2].
  const int rr   = t >> 2;                 // 0..63
  const int ssrc = ((t & 3) ^ ((t >> 3) & 3)) << 4;
  const signed char* pa = A8 + (size_t)(bm * BM + rr) * K_TOTAL + ssrc;
  const signed char* pb = B8 + (size_t)(bn * BN + rr) * K_TOTAL + ssrc;

#define GLL(gp, lp) __builtin_amdgcn_global_load_lds( \
      (const __attribute__((address_space(1))) unsigned int*)(gp), \
      (__attribute__((address_space(3))) unsigned int*)(lp), 16, 0, 0)

  auto stage = [&](int slot, size_t kt) {           // 6 GLL: A 16KB + B 8KB
#pragma unroll
    for (int g = 0; g < 4; ++g)
      GLL(pa + (size_t)g * 64 * K_TOTAL + kt, &ldsA[slot][g * 4096 + t * 16]);
#pragma unroll
    for (int g = 0; g < 2; ++g)
      GLL(pb + (size_t)g * 64 * K_TOTAL + kt, &ldsB[slot][g * 4096 + t * 16]);
  };

  i32x4 acc[8][4] = {};

  const int abase = (wm * 128 + fr) * BKI + sxs;
  const int bbase = (wn * 64 + fr) * BKI + sxs;

  // Prologue: stage slots 0,1; drain own stage(0) (stage(1) stays in flight);
  // barrier -> slot 0 fully staged across all waves before tile 0's reads.
  stage(0, 0);
  stage(1, BKI);
  asm volatile("s_waitcnt vmcnt(6)" ::: "memory");
  SCHED0();
  __builtin_amdgcn_s_barrier();
  SCHED0();

  int cur = 0;
  for (int t0 = 0; t0 < NTI; ++t0) {
    // Reads of tile t0 (slot published by prologue [t0=0] or iter t0-1's
    // barrier).
    const signed char* Ab = &ldsA[cur][abase];
    const signed char* Bb = &ldsB[cur][bbase];
    i32x4 a_[8], b_[4];
#pragma unroll
    for (int nf = 0; nf < 4; ++nf) b_[nf] = *(const i32x4*)&Bb[nf * 16 * BKI];
#pragma unroll
    for (int mf = 0; mf < 8; ++mf) a_[mf] = *(const i32x4*)&Ab[mf * 16 * BKI];
    SCHED0();

    int s2 = cur + 2; if (s2 >= 3) s2 -= 3;
    const bool hasStage = (t0 + 2 < NTI);
    if (hasStage) stage(s2, (size_t)(t0 + 2) * BKI);
    SCHED0();
    if (hasStage) { asm volatile("s_waitcnt vmcnt(6)" ::: "memory"); }
    else          { asm volatile("s_waitcnt vmcnt(0)" ::: "memory"); }
    asm volatile("s_waitcnt lgkmcnt(0)" ::: "memory");
    SCHED0();
    __builtin_amdgcn_s_barrier();            // publish slot t0+1; reads done
    SCHED0();

    __builtin_amdgcn_s_setprio(1);
#pragma unroll
    for (int mf = 0; mf < 8; ++mf)
#pragma unroll
      for (int nf = 0; nf < 4; ++nf)
        acc[mf][nf] = MFMAI(a_[mf], b_[nf], acc[mf][nf]);
    __builtin_amdgcn_s_setprio(0);
    SCHED0();

    ++cur; if (cur >= 3) cur = 0;
  }

  // Epilogue: C/D layout col = lane&15, row = (lane>>4)*4 + reg (dtype-indep).
  const int row0 = bm * BM + wm * 128 + kg * 4;
  const int col0 = bn * BN + wn * 64 + fr;
  float qv[8][4];
#pragma unroll
  for (int m = 0; m < 8; ++m)
#pragma unroll
    for (int r = 0; r < 4; ++r) qv[m][r] = qrow[row0 + m * 16 + r];
#pragma unroll
  for (int nf = 0; nf < 4; ++nf) {
    const int gc = col0 + nf * 16;
    const float s  = scales[gc];
    const float bv = bias[gc];
#pragma unroll
    for (int m = 0; m < 8; ++m) {
      const int gr = row0 + m * 16;
#pragma unroll
      for (int r = 0; r < 4; ++r)
        C[(size_t)(gr + r) * N_TOTAL + gc] = (float)acc[m][nf][r] * (qv[m][r] * s) + bv;
    }
  }
#undef GLL
}

// Fallback if workspace is too small: correct but slow.
__global__ void naive_int4_kernel(const float* __restrict__ x,
                                  const int* __restrict__ wq,
                                  const float* __restrict__ scales,
                                  const float* __restrict__ bias,
                                  float* __restrict__ out) {
  size_t idx = (size_t)blockIdx.x * blockDim.x + threadIdx.x;
  int o = (int)(idx & (N_TOTAL - 1));
  int m = (int)(idx >> 12);
  const float* xr = x + (size_t)m * K_TOTAL;
  const int* wrow = wq + (size_t)o * (K_TOTAL / 2);
  float acc = 0.f;
  for (int j = 0; j < K_TOTAL / 2; ++j) {
    int b = wrow[j];
    int lo = ((b & 0xF) ^ 8) - 8;
    int hi = (((b >> 4) & 0xF) ^ 8) - 8;
    acc += xr[2 * j] * (float)lo + xr[2 * j + 1] * (float)hi;
  }
  out[idx] = acc * scales[o] + bias[o];
}

extern "C" void kernel_launch(void* const* d_in, const int* in_sizes, int n_in,
                              void* d_out, int out_size, void* d_ws, size_t ws_size,
                              hipStream_t stream) {
  const float* x      = (const float*)d_in[0];
  const int*   wq     = (const int*)d_in[1];
  const float* scales = (const float*)d_in[2];
  const float* bias   = (const float*)d_in[3];
  float* out = (float*)d_out;

  const size_t needXQ = (size_t)M_TOTAL * K_TOTAL;                 // 67.1 MB
  const size_t needW8 = (size_t)N_TOTAL * K_TOTAL;                 // 16.8 MB
  const size_t needQ  = (size_t)M_TOTAL * sizeof(float);           // 64 KB

  if (d_ws != nullptr && ws_size >= needXQ + needW8 + needQ) {
    signed char* xq = (signed char*)d_ws;
    signed char* w8 = (signed char*)d_ws + needXQ;
    float* qrow = (float*)((char*)d_ws + needXQ + needW8);
    quant_x_kernel<<<M_TOTAL, 256, 0, stream>>>(x, xq, qrow);
    dequant_w8_kernel<<<1024, 256, 0, stream>>>(wq, w8);
    gemm256_i8_kernel<<<(M_TOTAL / BM) * (N_TOTAL / BN), 256, 0, stream>>>(
        xq, w8, qrow, scales, bias, out);
  } else {
    const size_t total = (size_t)M_TOTAL * N_TOTAL;
    naive_int4_kernel<<<(unsigned)(total / 256), 256, 0, stream>>>(x, wq, scales, bias, out);
  }
}